// Round 18
// baseline (301.177 us; speedup 1.0000x reference)
//
#include <hip/hip_runtime.h>
#include <hip/hip_bf16.h>

#define N_NODES 100000
#define N_EDGES 1600000
#define D_IN 64
#define D_OUT 64
#define E_DIM 32
#define KCAT 288            // 3*64 (S buckets) + 3*32 (T buckets)
#define NK (4 * N_NODES)    // sort keys: 4*dst + etype (slot 3 unused -> count 0)
#define NBCHUNK 391         // ceil(NK / 1024)

typedef unsigned long long u64;
typedef __hip_bfloat16 bf16;
typedef unsigned char u8;
typedef __attribute__((ext_vector_type(8))) short bf16x8v;  // MFMA A/B frag (4 VGPRs)
typedef __attribute__((ext_vector_type(4))) float f32x4v;   // MFMA C/D frag

__device__ __forceinline__ float bflo(unsigned u) {
    union { unsigned v; float f; } x; x.v = u << 16; return x.f;
}
__device__ __forceinline__ float bfhi(unsigned u) {
    union { unsigned v; float f; } x; x.v = u & 0xffff0000u; return x.f;
}
__device__ __forceinline__ unsigned packbf2(float a, float b) {
    union { bf16 h[2]; unsigned u; } w;
    w.h[0] = __float2bfloat16(a); w.h[1] = __float2bfloat16(b);
    return w.u;
}

// ---------------------------------------------------------------------------
// zero helper (capture-safe) -- fallback path only
// ---------------------------------------------------------------------------
__global__ __launch_bounds__(256) void zero_buf(float4* __restrict__ p, long n4) {
    long i = (long)blockIdx.x * 256 + threadIdx.x;
    long stride = (long)gridDim.x * 256;
    float4 z = make_float4(0.f, 0.f, 0.f, 0.f);
    for (; i < n4; i += stride) p[i] = z;
}

// ---------------------------------------------------------------------------
// node_xform_g: GEMM-style microtile (64 nodes x 64 cols / block).
// Also zeroes cnt[] (fused; stream order guarantees it precedes count_rank).
// ---------------------------------------------------------------------------
__global__ __launch_bounds__(256) void node_xform_g(const float* __restrict__ nf,
                                                    const float* __restrict__ Wn,
                                                    const int* __restrict__ ntype,
                                                    bf16* __restrict__ xout,
                                                    int* __restrict__ cnt) {
    __shared__ float Ws[2 * 64 * 64];   // [t][k][j], 32 KB
    __shared__ float As[64][65];        // [row][k], padded
    int tid = threadIdx.x;
    int n0 = blockIdx.x * 64;
    {   // fused cnt zeroing (1563*256 = 400128 >= NK)
        int zi = blockIdx.x * 256 + tid;
        if (zi < NK) cnt[zi] = 0;
    }
    for (int i = tid; i < 2 * 64 * 64; i += 256) Ws[i] = Wn[i];
#pragma unroll
    for (int i = 0; i < 4; ++i) {
        int f = (i * 256 + tid) * 4;
        int r = f >> 6, c = f & 63;
        int n = n0 + r;
        float4 v = (n < N_NODES) ? *(const float4*)&nf[(size_t)n * 64 + c]
                                 : make_float4(0.f, 0.f, 0.f, 0.f);
        As[r][c + 0] = v.x; As[r][c + 1] = v.y; As[r][c + 2] = v.z; As[r][c + 3] = v.w;
    }
    __syncthreads();
    int tx = tid & 15, ty = tid >> 4;
    int r0 = n0 + ty * 4;
    int t0 = (r0 + 0 < N_NODES) ? ntype[r0 + 0] : 0;
    int t1 = (r0 + 1 < N_NODES) ? ntype[r0 + 1] : 0;
    int t2 = (r0 + 2 < N_NODES) ? ntype[r0 + 2] : 0;
    int t3 = (r0 + 3 < N_NODES) ? ntype[r0 + 3] : 0;
    float4 acc0 = {0,0,0,0}, acc1 = {0,0,0,0}, acc2 = {0,0,0,0}, acc3 = {0,0,0,0};
#pragma unroll 8
    for (int k = 0; k < 64; ++k) {
        float4 w0 = *(const float4*)&Ws[k * 64 + tx * 4];
        float4 w1 = *(const float4*)&Ws[4096 + k * 64 + tx * 4];
        float a0 = As[ty * 4 + 0][k];
        float a1 = As[ty * 4 + 1][k];
        float a2 = As[ty * 4 + 2][k];
        float a3 = As[ty * 4 + 3][k];
        float4 wa = t0 ? w1 : w0;
        float4 wb = t1 ? w1 : w0;
        float4 wc = t2 ? w1 : w0;
        float4 wd = t3 ? w1 : w0;
        acc0.x = fmaf(a0, wa.x, acc0.x); acc0.y = fmaf(a0, wa.y, acc0.y);
        acc0.z = fmaf(a0, wa.z, acc0.z); acc0.w = fmaf(a0, wa.w, acc0.w);
        acc1.x = fmaf(a1, wb.x, acc1.x); acc1.y = fmaf(a1, wb.y, acc1.y);
        acc1.z = fmaf(a1, wb.z, acc1.z); acc1.w = fmaf(a1, wb.w, acc1.w);
        acc2.x = fmaf(a2, wc.x, acc2.x); acc2.y = fmaf(a2, wc.y, acc2.y);
        acc2.z = fmaf(a2, wc.z, acc2.z); acc2.w = fmaf(a2, wc.w, acc2.w);
        acc3.x = fmaf(a3, wd.x, acc3.x); acc3.y = fmaf(a3, wd.y, acc3.y);
        acc3.z = fmaf(a3, wd.z, acc3.z); acc3.w = fmaf(a3, wd.w, acc3.w);
    }
#pragma unroll
    for (int r = 0; r < 4; ++r) {
        int n = r0 + r;
        if (n < N_NODES) {
            float4 a = (r == 0) ? acc0 : (r == 1) ? acc1 : (r == 2) ? acc2 : acc3;
            union { bf16 h[4]; uint2 u; } pk;
            pk.h[0] = __float2bfloat16(a.x); pk.h[1] = __float2bfloat16(a.y);
            pk.h[2] = __float2bfloat16(a.z); pk.h[3] = __float2bfloat16(a.w);
            *(uint2*)&xout[(size_t)n * 64 + tx * 4] = pk.u;
        }
    }
}

// ---------------------------------------------------------------------------
// count + rank: 1 edge/thread; writes packed krank = (key<<8)|rank
// ---------------------------------------------------------------------------
__global__ __launch_bounds__(256) void count_rank(const int* __restrict__ eidx,
                                                  const int* __restrict__ etype,
                                                  int* __restrict__ cnt,
                                                  int* __restrict__ krank) {
    int i = blockIdx.x * 256 + threadIdx.x;
    if (i >= N_EDGES) return;
    int d = eidx[N_EDGES + i];
    int t = etype[i];
    int key = 4 * d + t;
    int r = atomicAdd(&cnt[key], 1);
    krank[i] = (key << 8) | r;
}

__global__ __launch_bounds__(256) void scan_a(const int* __restrict__ cnt,
                                              int* __restrict__ partials) {
    __shared__ int ws[4];
    int b = blockIdx.x, tid = threadIdx.x, lane = tid & 63, wid = tid >> 6;
    int i0 = b * 1024 + tid * 4;
    int s = 0;
#pragma unroll
    for (int k = 0; k < 4; ++k) { int i = i0 + k; if (i < NK) s += cnt[i]; }
#pragma unroll
    for (int d = 32; d > 0; d >>= 1) s += __shfl_down(s, d);
    if (lane == 0) ws[wid] = s;
    __syncthreads();
    if (tid == 0) partials[b] = ws[0] + ws[1] + ws[2] + ws[3];
}

// scan_c with FUSED partials scan (no scan_b launch).
__global__ __launch_bounds__(256) void scan_c(const int* __restrict__ cnt,
                                              const int* __restrict__ partials,
                                              int* __restrict__ offs) {
    __shared__ int sp[512];
    __shared__ int wsum[4];
    int tid = threadIdx.x;
    sp[tid]       = (tid < NBCHUNK) ? partials[tid] : 0;
    sp[tid + 256] = (tid + 256 < NBCHUNK) ? partials[tid + 256] : 0;
    __syncthreads();
    for (int d = 1; d < 512; d <<= 1) {
        int u0 = (tid >= d) ? sp[tid - d] : 0;
        int u1 = sp[tid + 256 - d];
        __syncthreads();
        sp[tid] += u0; sp[tid + 256] += u1;
        __syncthreads();
    }
    int b = blockIdx.x;
    int pex = (b == 0) ? 0 : sp[b - 1];

    int lane = tid & 63, wid = tid >> 6;
    int i0 = b * 1024 + tid * 4;
    int c0 = (i0 + 0 < NK) ? cnt[i0 + 0] : 0;
    int c1 = (i0 + 1 < NK) ? cnt[i0 + 1] : 0;
    int c2 = (i0 + 2 < NK) ? cnt[i0 + 2] : 0;
    int c3 = (i0 + 3 < NK) ? cnt[i0 + 3] : 0;
    int lsum = c0 + c1 + c2 + c3;
    int v = lsum;
#pragma unroll
    for (int d = 1; d < 64; d <<= 1) {
        int u = __shfl_up(v, d);
        if (lane >= d) v += u;
    }
    int wexcl = v - lsum;
    if (lane == 63) wsum[wid] = v;
    __syncthreads();
    int bexcl = 0;
    for (int w = 0; w < wid; ++w) bexcl += wsum[w];
    int base = pex + bexcl + wexcl;
    if (i0 + 0 < NK) offs[i0 + 0] = base; base += c0;
    if (i0 + 1 < NK) offs[i0 + 1] = base; base += c1;
    if (i0 + 2 < NK) offs[i0 + 2] = base; base += c2;
    if (i0 + 3 < NK) offs[i0 + 3] = base;
}

// ---------------------------------------------------------------------------
// place_pay: 8B payload scatter (pos = offs[key]+rank, no atomics).
// ---------------------------------------------------------------------------
__global__ __launch_bounds__(256) void place_pay(const int* __restrict__ eidx,
                                                 const int* __restrict__ krank,
                                                 const int* __restrict__ offs,
                                                 u64* __restrict__ pay) {
    int i = blockIdx.x * 256 + threadIdx.x;
    if (i >= N_EDGES) return;
    int kr = krank[i];
    int key = (int)((unsigned)kr >> 8);
    int r = kr & 255;
    int s = eidx[i];
    int pos = offs[key] + r;
    pay[pos] = (u64)(unsigned)s | ((u64)(unsigned)i << 32);
}

// ---------------------------------------------------------------------------
// aggregate_g: round-16/17 structure (PAIRED loads, shared ds_bpermute
// broadcast, 16-edge step, offs+pay prefetch pipeline). Zero atomics.
// ---------------------------------------------------------------------------
__global__ __launch_bounds__(256) void aggregate_g(const u64* __restrict__ pay,
                                                   const int* __restrict__ offs,
                                                   const bf16* __restrict__ xout,
                                                   const float* __restrict__ ef,
                                                   bf16* __restrict__ B) {
    int wid = threadIdx.x >> 6, lane = threadIdx.x & 63;
    int gw = blockIdx.x * 4 + wid, nw = gridDim.x * 4;
    int c = lane & 31, half = lane >> 5;
    int h4 = half << 2;                         // bpermute byte-addr offset
    const unsigned* xo32 = (const unsigned*)xout;   // row = 32 uints (64 bf16)
    if (gw >= N_NODES) return;

    int4 o = ((const int4*)offs)[gw];
    u64 p = 0ull;
    {
        int beg = __builtin_amdgcn_readfirstlane(o.x);
        int end = __builtin_amdgcn_readfirstlane(o.w);
        if (beg + lane < end) p = pay[beg + lane];
    }

    for (int n = gw; n < N_NODES; n += nw) {
        int nn = n + nw;
        int4 onext = make_int4(0, 0, 0, 0);
        u64 pnext = 0ull;
        if (nn < N_NODES) {
            onext = ((const int4*)offs)[nn];
            int nbeg = __builtin_amdgcn_readfirstlane(onext.x);
            int nend = __builtin_amdgcn_readfirstlane(onext.w);
            if (nbeg + lane < nend) pnext = pay[nbeg + lane];   // overlaps compute
        }
        int beg = __builtin_amdgcn_readfirstlane(o.x);
        int y   = __builtin_amdgcn_readfirstlane(o.y);
        int z   = __builtin_amdgcn_readfirstlane(o.z);
        int end = __builtin_amdgcn_readfirstlane(o.w);
        float2 xa = make_float2(0.f, 0.f), xb = make_float2(0.f, 0.f), xc = make_float2(0.f, 0.f);
        float ea = 0.f, eb = 0.f, ec = 0.f;

        u64 pcur = p;
        for (int base = beg; base < end; base += 64) {
            int m = end - base; if (m > 64) m = 64;
            if (base != beg) pcur = (lane < m) ? pay[base + lane] : 0ull;  // rare (deg>64)
            int plo = (int)(unsigned)pcur;            // src
            int phi = (int)(unsigned)(pcur >> 32);    // edge id
            for (int j = 0; j < m; j += 16) {
                int sgp[8], egp[8];
#pragma unroll
                for (int q = 0; q < 8; ++q) {
                    int baddr = ((j + 2 * q) << 2) + h4;   // lane idx j+2q+half, x4
                    sgp[q] = __builtin_amdgcn_ds_bpermute(baddr, plo);
                    egp[q] = __builtin_amdgcn_ds_bpermute(baddr, phi);
                }
                unsigned xv[8];
                float evv[8];
#pragma unroll
                for (int q = 0; q < 8; ++q) {
                    xv[q]  = xo32[(unsigned)sgp[q] * 32u + (unsigned)c];
                    evv[q] = ef[(unsigned)egp[q] * 32u + (unsigned)c];
                }
#pragma unroll
                for (int q = 0; q < 8; ++q) {
                    float2 x2v = make_float2(bflo(xv[q]), bfhi(xv[q]));
                    float ev = evv[q];
                    int i0 = base + j + 2 * q;     // scalar
                    if (i0 + 1 < y) {                                   // pair in seg0
                        xa.x += x2v.x; xa.y += x2v.y; ea += ev;
                    } else if (i0 >= y && i0 + 1 < z) {                 // pair in seg1
                        xb.x += x2v.x; xb.y += x2v.y; eb += ev;
                    } else if (i0 >= z && i0 + 1 < end) {               // pair in seg2
                        xc.x += x2v.x; xc.y += x2v.y; ec += ev;
                    } else {                                            // boundary / tail
                        int idx = i0 + half;
                        bool v = idx < end;
                        float fl = v ? x2v.x : 0.f, fh = v ? x2v.y : 0.f, fe = v ? ev : 0.f;
                        if (idx < y)      { xa.x += fl; xa.y += fh; ea += fe; }
                        else if (idx < z) { xb.x += fl; xb.y += fh; eb += fe; }
                        else              { xc.x += fl; xc.y += fh; ec += fe; }
                    }
                }
            }
        }
        // fold the two halves
        xa.x += __shfl_down(xa.x, 32); xa.y += __shfl_down(xa.y, 32);
        xb.x += __shfl_down(xb.x, 32); xb.y += __shfl_down(xb.y, 32);
        xc.x += __shfl_down(xc.x, 32); xc.y += __shfl_down(xc.y, 32);
        ea   += __shfl_down(ea, 32);   eb   += __shfl_down(eb, 32);   ec += __shfl_down(ec, 32);

        if (lane < 32) {
            bf16* Bn = B + (size_t)n * KCAT;
            *(unsigned*)&Bn[2 * c]       = packbf2(xa.x, xa.y);
            *(unsigned*)&Bn[64 + 2 * c]  = packbf2(xb.x, xb.y);
            *(unsigned*)&Bn[128 + 2 * c] = packbf2(xc.x, xc.y);
            Bn[192 + c] = __float2bfloat16(ea);
            Bn[224 + c] = __float2bfloat16(eb);
            Bn[256 + c] = __float2bfloat16(ec);
        }
        o = onext;
        p = pnext;
    }
}

// ---------------------------------------------------------------------------
// final_gemm_mfma: out = B(bf16) @ Wcat(bf16 in LDS, transposed+padded).
// 64 nodes x 64 cols per block, 4 waves; each wave: 16x64 strip, 9 K-steps
// of mfma_f32_16x16x32_bf16 x 4 col-tiles.
//   A-frag: lane l -> row l&15, k = 8*(l>>4)+j  (one uint4 gload/K-step)
//   B-frag: WT[c0+(l&15)][kk*32+8*(l>>4)]       (one ds_read_b128)
//   C/D:    col = l&15, row = (l>>4)*4 + reg    (guide §3, HW-verified)
// WT pad 312 shorts/row: bank stride 28dw -> 2-way conflict (free), 16B-aligned.
// ---------------------------------------------------------------------------
__global__ __launch_bounds__(256) void final_gemm_mfma(const bf16* __restrict__ Bb,
                                                       const float* __restrict__ Wm,
                                                       float* __restrict__ out) {
    __shared__ short WT[64][312];   // WcatT bf16, 39 KB
    int tid = threadIdx.x;
    // stage WcatT: 2304 chunks of 8 k-elems; 9 chunks/thread
#pragma unroll
    for (int i = 0; i < 9; ++i) {
        int ch = i * 256 + tid;          // chunk id
        int j  = ch / 36;                // col 0..63
        int rc = (ch % 36) * 8;          // k base 0..280
        union { short s[8]; uint4 u; } pk;
#pragma unroll
        for (int q = 0; q < 8; ++q) {
            int r = rc + q;
            int t, kin;
            if (r < 192) { t = r >> 6; kin = r & 63; }
            else         { int s2 = r - 192; t = s2 >> 5; kin = 64 + (s2 & 31); }
            union { bf16 h; short s; } cv;
            cv.h = __float2bfloat16(Wm[(t * 96 + kin) * 64 + j]);
            pk.s[q] = cv.s;
        }
        *(uint4*)&WT[j][rc] = pk.u;
    }
    __syncthreads();

    int w = tid >> 6, l = tid & 63;
    int lrow = l & 15;
    int lk = (l >> 4) * 8;               // k sub-offset within K=32 step
    int nbase = blockIdx.x * 64 + w * 16;
    int node = nbase + lrow;
    int nodec = (node < N_NODES) ? node : (N_NODES - 1);   // clamp (padded rows unused)
    const bf16* arow = Bb + (size_t)nodec * KCAT + lk;
    f32x4v acc0 = {0.f, 0.f, 0.f, 0.f}, acc1 = acc0, acc2 = acc0, acc3 = acc0;
#pragma unroll
    for (int kk = 0; kk < 9; ++kk) {
        bf16x8v a  = *(const bf16x8v*)(arow + kk * 32);
        bf16x8v b0 = *(const bf16x8v*)&WT[ 0 + lrow][kk * 32 + lk];
        bf16x8v b1 = *(const bf16x8v*)&WT[16 + lrow][kk * 32 + lk];
        bf16x8v b2 = *(const bf16x8v*)&WT[32 + lrow][kk * 32 + lk];
        bf16x8v b3 = *(const bf16x8v*)&WT[48 + lrow][kk * 32 + lk];
        acc0 = __builtin_amdgcn_mfma_f32_16x16x32_bf16(a, b0, acc0, 0, 0, 0);
        acc1 = __builtin_amdgcn_mfma_f32_16x16x32_bf16(a, b1, acc1, 0, 0, 0);
        acc2 = __builtin_amdgcn_mfma_f32_16x16x32_bf16(a, b2, acc2, 0, 0, 0);
        acc3 = __builtin_amdgcn_mfma_f32_16x16x32_bf16(a, b3, acc3, 0, 0, 0);
    }
    int col = l & 15;
    int row0 = (l >> 4) * 4;
#pragma unroll
    for (int r = 0; r < 4; ++r) {
        int n = nbase + row0 + r;
        if (n < N_NODES) {
            float* on = out + (size_t)n * 64;
            on[ 0 + col] = acc0[r];
            on[16 + col] = acc1[r];
            on[32 + col] = acc2[r];
            on[48 + col] = acc3[r];
        }
    }
}

// ---------------------------------------------------------------------------
// Fallback (ws tiny): direct wave-per-edge, fp32.
// ---------------------------------------------------------------------------
__global__ __launch_bounds__(256) void fallback_edge(const float* __restrict__ nf,
                                                     const float* __restrict__ ef,
                                                     const float* __restrict__ Wn,
                                                     const float* __restrict__ Wm,
                                                     const int* __restrict__ ntype,
                                                     const int* __restrict__ etype,
                                                     const int* __restrict__ eidx,
                                                     float* __restrict__ out) {
    __shared__ float wn[2 * 64 * 64];
    __shared__ float wm[3 * 96 * 64];
    for (int i = threadIdx.x; i < 2 * 64 * 64; i += 256) wn[i] = Wn[i];
    for (int i = threadIdx.x; i < 3 * 96 * 64; i += 256) wm[i] = Wm[i];
    __syncthreads();
    int wid = threadIdx.x >> 6, lane = threadIdx.x & 63;
    for (int e = blockIdx.x * 4 + wid; e < N_EDGES; e += gridDim.x * 4) {
        int t = etype[e];
        int s = eidx[e];
        int d = eidx[N_EDGES + e];
        int nt = ntype[s];
        float xs = nf[(long)s * 64 + lane];
        const float* wcol = &wn[nt * 4096 + lane];
        float xo = 0.f;
#pragma unroll 16
        for (int k = 0; k < 64; ++k) xo = fmaf(__shfl(xs, k), wcol[k * 64], xo);
        float ev = ef[(long)e * 32 + (lane & 31)];
        const float* mcol = &wm[t * 96 * 64 + lane];
        float m = 0.f;
#pragma unroll 16
        for (int k = 0; k < 64; ++k) m = fmaf(__shfl(xo, k), mcol[k * 64], m);
#pragma unroll 8
        for (int k = 0; k < 32; ++k) m = fmaf(__shfl(ev, k), mcol[(64 + k) * 64], m);
        atomicAdd(&out[(long)d * 64 + lane], m);
    }
}

// ---------------------------------------------------------------------------
extern "C" void kernel_launch(void* const* d_in, const int* in_sizes, int n_in,
                              void* d_out, int out_size, void* d_ws, size_t ws_size,
                              hipStream_t stream) {
    const float* nf    = (const float*)d_in[0];
    const float* ef    = (const float*)d_in[1];
    const float* Wn    = (const float*)d_in[2];
    const float* Wm    = (const float*)d_in[3];
    const int*   ntype = (const int*)d_in[4];
    const int*   etype = (const int*)d_in[5];
    const int*   eidx  = (const int*)d_in[6];
    float* out = (float*)d_out;

    const size_t xout_bytes = (size_t)N_NODES * 64 * 2;        // 12.8 MB bf16
    const size_t b_bytes    = (size_t)N_NODES * KCAT * 2;      // 57.6 MB bf16

    if (ws_size >= xout_bytes + b_bytes) {
        bf16* xout = (bf16*)d_ws;
        bf16* B    = (bf16*)((char*)d_ws + xout_bytes);
        // scratch in d_out (22.4 MB < 25.6 MB); final_gemm fully overwrites
        // d_out at the end of every call.
        u64* pay      = (u64*)d_out;            // 12.8 MB
        int* cnt      = (int*)(pay + N_EDGES);  // 1.6 MB
        int* offs     = cnt + NK;               // 1.6 MB
        int* partials = offs + NK;              // 2 KB (pad 512)
        int* krank    = partials + 512;         // 6.4 MB

        node_xform_g<<<(N_NODES + 63) / 64, 256, 0, stream>>>(nf, Wn, ntype, xout, cnt);
        count_rank<<<(N_EDGES + 255) / 256, 256, 0, stream>>>(eidx, etype, cnt, krank);
        scan_a<<<NBCHUNK, 256, 0, stream>>>(cnt, partials);
        scan_c<<<NBCHUNK, 256, 0, stream>>>(cnt, partials, offs);
        place_pay<<<(N_EDGES + 255) / 256, 256, 0, stream>>>(eidx, krank, offs, pay);
        aggregate_g<<<4096, 256, 0, stream>>>(pay, offs, xout, ef, B);
        final_gemm_mfma<<<(N_NODES + 63) / 64, 256, 0, stream>>>(B, Wm, out);
    } else {
        zero_buf<<<2048, 256, 0, stream>>>((float4*)d_out, (long)((size_t)out_size * 4 / 16));
        fallback_edge<<<4096, 256, 0, stream>>>(nf, ef, Wn, Wm, ntype, etype, eidx, out);
    }
}

// Round 19
// 255.477 us; speedup vs baseline: 1.1789x; 1.1789x over previous
//
#include <hip/hip_runtime.h>
#include <hip/hip_bf16.h>

#define N_NODES 100000
#define N_EDGES 1600000
#define D_IN 64
#define D_OUT 64
#define E_DIM 32
#define KCAT 288            // 3*64 (S buckets) + 3*32 (T buckets)
#define NK (4 * N_NODES)    // sort keys: 4*dst + etype (slot 3 unused -> count 0)
#define NBCHUNK 391         // ceil(NK / 1024)

typedef unsigned long long u64;
typedef __hip_bfloat16 bf16;
typedef unsigned char u8;
typedef __attribute__((ext_vector_type(8))) short bf16x8v;  // MFMA A/B frag (4 VGPRs)
typedef __attribute__((ext_vector_type(4))) float f32x4v;   // MFMA C/D frag

__device__ __forceinline__ float bflo(unsigned u) {
    union { unsigned v; float f; } x; x.v = u << 16; return x.f;
}
__device__ __forceinline__ float bfhi(unsigned u) {
    union { unsigned v; float f; } x; x.v = u & 0xffff0000u; return x.f;
}
__device__ __forceinline__ unsigned packbf2(float a, float b) {
    union { bf16 h[2]; unsigned u; } w;
    w.h[0] = __float2bfloat16(a); w.h[1] = __float2bfloat16(b);
    return w.u;
}
__device__ __forceinline__ short sbf(float f) {
    union { bf16 h; short s; } cv; cv.h = __float2bfloat16(f); return cv.s;
}

// ---------------------------------------------------------------------------
// zero helper (capture-safe) -- fallback path only
// ---------------------------------------------------------------------------
__global__ __launch_bounds__(256) void zero_buf(float4* __restrict__ p, long n4) {
    long i = (long)blockIdx.x * 256 + threadIdx.x;
    long stride = (long)gridDim.x * 256;
    float4 z = make_float4(0.f, 0.f, 0.f, 0.f);
    for (; i < n4; i += stride) p[i] = z;
}

// ---------------------------------------------------------------------------
// node_xform_g: GEMM-style microtile (64 nodes x 64 cols / block).
// Also zeroes cnt[] (fused; stream order guarantees it precedes count_rank).
// ---------------------------------------------------------------------------
__global__ __launch_bounds__(256) void node_xform_g(const float* __restrict__ nf,
                                                    const float* __restrict__ Wn,
                                                    const int* __restrict__ ntype,
                                                    bf16* __restrict__ xout,
                                                    int* __restrict__ cnt) {
    __shared__ float Ws[2 * 64 * 64];   // [t][k][j], 32 KB
    __shared__ float As[64][65];        // [row][k], padded
    int tid = threadIdx.x;
    int n0 = blockIdx.x * 64;
    {   // fused cnt zeroing (1563*256 = 400128 >= NK)
        int zi = blockIdx.x * 256 + tid;
        if (zi < NK) cnt[zi] = 0;
    }
    for (int i = tid; i < 2 * 64 * 64; i += 256) Ws[i] = Wn[i];
#pragma unroll
    for (int i = 0; i < 4; ++i) {
        int f = (i * 256 + tid) * 4;
        int r = f >> 6, c = f & 63;
        int n = n0 + r;
        float4 v = (n < N_NODES) ? *(const float4*)&nf[(size_t)n * 64 + c]
                                 : make_float4(0.f, 0.f, 0.f, 0.f);
        As[r][c + 0] = v.x; As[r][c + 1] = v.y; As[r][c + 2] = v.z; As[r][c + 3] = v.w;
    }
    __syncthreads();
    int tx = tid & 15, ty = tid >> 4;
    int r0 = n0 + ty * 4;
    int t0 = (r0 + 0 < N_NODES) ? ntype[r0 + 0] : 0;
    int t1 = (r0 + 1 < N_NODES) ? ntype[r0 + 1] : 0;
    int t2 = (r0 + 2 < N_NODES) ? ntype[r0 + 2] : 0;
    int t3 = (r0 + 3 < N_NODES) ? ntype[r0 + 3] : 0;
    float4 acc0 = {0,0,0,0}, acc1 = {0,0,0,0}, acc2 = {0,0,0,0}, acc3 = {0,0,0,0};
#pragma unroll 8
    for (int k = 0; k < 64; ++k) {
        float4 w0 = *(const float4*)&Ws[k * 64 + tx * 4];
        float4 w1 = *(const float4*)&Ws[4096 + k * 64 + tx * 4];
        float a0 = As[ty * 4 + 0][k];
        float a1 = As[ty * 4 + 1][k];
        float a2 = As[ty * 4 + 2][k];
        float a3 = As[ty * 4 + 3][k];
        float4 wa = t0 ? w1 : w0;
        float4 wb = t1 ? w1 : w0;
        float4 wc = t2 ? w1 : w0;
        float4 wd = t3 ? w1 : w0;
        acc0.x = fmaf(a0, wa.x, acc0.x); acc0.y = fmaf(a0, wa.y, acc0.y);
        acc0.z = fmaf(a0, wa.z, acc0.z); acc0.w = fmaf(a0, wa.w, acc0.w);
        acc1.x = fmaf(a1, wb.x, acc1.x); acc1.y = fmaf(a1, wb.y, acc1.y);
        acc1.z = fmaf(a1, wb.z, acc1.z); acc1.w = fmaf(a1, wb.w, acc1.w);
        acc2.x = fmaf(a2, wc.x, acc2.x); acc2.y = fmaf(a2, wc.y, acc2.y);
        acc2.z = fmaf(a2, wc.z, acc2.z); acc2.w = fmaf(a2, wc.w, acc2.w);
        acc3.x = fmaf(a3, wd.x, acc3.x); acc3.y = fmaf(a3, wd.y, acc3.y);
        acc3.z = fmaf(a3, wd.z, acc3.z); acc3.w = fmaf(a3, wd.w, acc3.w);
    }
#pragma unroll
    for (int r = 0; r < 4; ++r) {
        int n = r0 + r;
        if (n < N_NODES) {
            float4 a = (r == 0) ? acc0 : (r == 1) ? acc1 : (r == 2) ? acc2 : acc3;
            union { bf16 h[4]; uint2 u; } pk;
            pk.h[0] = __float2bfloat16(a.x); pk.h[1] = __float2bfloat16(a.y);
            pk.h[2] = __float2bfloat16(a.z); pk.h[3] = __float2bfloat16(a.w);
            *(uint2*)&xout[(size_t)n * 64 + tx * 4] = pk.u;
        }
    }
}

// ---------------------------------------------------------------------------
// count + rank: 1 edge/thread; writes packed krank = (key<<8)|rank
// ---------------------------------------------------------------------------
__global__ __launch_bounds__(256) void count_rank(const int* __restrict__ eidx,
                                                  const int* __restrict__ etype,
                                                  int* __restrict__ cnt,
                                                  int* __restrict__ krank) {
    int i = blockIdx.x * 256 + threadIdx.x;
    if (i >= N_EDGES) return;
    int d = eidx[N_EDGES + i];
    int t = etype[i];
    int key = 4 * d + t;
    int r = atomicAdd(&cnt[key], 1);
    krank[i] = (key << 8) | r;
}

__global__ __launch_bounds__(256) void scan_a(const int* __restrict__ cnt,
                                              int* __restrict__ partials) {
    __shared__ int ws[4];
    int b = blockIdx.x, tid = threadIdx.x, lane = tid & 63, wid = tid >> 6;
    int i0 = b * 1024 + tid * 4;
    int s = 0;
#pragma unroll
    for (int k = 0; k < 4; ++k) { int i = i0 + k; if (i < NK) s += cnt[i]; }
#pragma unroll
    for (int d = 32; d > 0; d >>= 1) s += __shfl_down(s, d);
    if (lane == 0) ws[wid] = s;
    __syncthreads();
    if (tid == 0) partials[b] = ws[0] + ws[1] + ws[2] + ws[3];
}

// scan_c with FUSED partials scan (no scan_b launch).
__global__ __launch_bounds__(256) void scan_c(const int* __restrict__ cnt,
                                              const int* __restrict__ partials,
                                              int* __restrict__ offs) {
    __shared__ int sp[512];
    __shared__ int wsum[4];
    int tid = threadIdx.x;
    sp[tid]       = (tid < NBCHUNK) ? partials[tid] : 0;
    sp[tid + 256] = (tid + 256 < NBCHUNK) ? partials[tid + 256] : 0;
    __syncthreads();
    for (int d = 1; d < 512; d <<= 1) {
        int u0 = (tid >= d) ? sp[tid - d] : 0;
        int u1 = sp[tid + 256 - d];
        __syncthreads();
        sp[tid] += u0; sp[tid + 256] += u1;
        __syncthreads();
    }
    int b = blockIdx.x;
    int pex = (b == 0) ? 0 : sp[b - 1];

    int lane = tid & 63, wid = tid >> 6;
    int i0 = b * 1024 + tid * 4;
    int c0 = (i0 + 0 < NK) ? cnt[i0 + 0] : 0;
    int c1 = (i0 + 1 < NK) ? cnt[i0 + 1] : 0;
    int c2 = (i0 + 2 < NK) ? cnt[i0 + 2] : 0;
    int c3 = (i0 + 3 < NK) ? cnt[i0 + 3] : 0;
    int lsum = c0 + c1 + c2 + c3;
    int v = lsum;
#pragma unroll
    for (int d = 1; d < 64; d <<= 1) {
        int u = __shfl_up(v, d);
        if (lane >= d) v += u;
    }
    int wexcl = v - lsum;
    if (lane == 63) wsum[wid] = v;
    __syncthreads();
    int bexcl = 0;
    for (int w = 0; w < wid; ++w) bexcl += wsum[w];
    int base = pex + bexcl + wexcl;
    if (i0 + 0 < NK) offs[i0 + 0] = base; base += c0;
    if (i0 + 1 < NK) offs[i0 + 1] = base; base += c1;
    if (i0 + 2 < NK) offs[i0 + 2] = base; base += c2;
    if (i0 + 3 < NK) offs[i0 + 3] = base;
}

// ---------------------------------------------------------------------------
// place_pay: 8B payload scatter (pos = offs[key]+rank, no atomics).
// ---------------------------------------------------------------------------
__global__ __launch_bounds__(256) void place_pay(const int* __restrict__ eidx,
                                                 const int* __restrict__ krank,
                                                 const int* __restrict__ offs,
                                                 u64* __restrict__ pay) {
    int i = blockIdx.x * 256 + threadIdx.x;
    if (i >= N_EDGES) return;
    int kr = krank[i];
    int key = (int)((unsigned)kr >> 8);
    int r = kr & 255;
    int s = eidx[i];
    int pos = offs[key] + r;
    pay[pos] = (u64)(unsigned)s | ((u64)(unsigned)i << 32);
}

// ---------------------------------------------------------------------------
// aggregate_g: PAIRED loads, shared ds_bpermute broadcast, 16-edge step,
// offs+pay prefetch pipeline. Zero atomics.
// ---------------------------------------------------------------------------
__global__ __launch_bounds__(256) void aggregate_g(const u64* __restrict__ pay,
                                                   const int* __restrict__ offs,
                                                   const bf16* __restrict__ xout,
                                                   const float* __restrict__ ef,
                                                   bf16* __restrict__ B) {
    int wid = threadIdx.x >> 6, lane = threadIdx.x & 63;
    int gw = blockIdx.x * 4 + wid, nw = gridDim.x * 4;
    int c = lane & 31, half = lane >> 5;
    int h4 = half << 2;                         // bpermute byte-addr offset
    const unsigned* xo32 = (const unsigned*)xout;   // row = 32 uints (64 bf16)
    if (gw >= N_NODES) return;

    int4 o = ((const int4*)offs)[gw];
    u64 p = 0ull;
    {
        int beg = __builtin_amdgcn_readfirstlane(o.x);
        int end = __builtin_amdgcn_readfirstlane(o.w);
        if (beg + lane < end) p = pay[beg + lane];
    }

    for (int n = gw; n < N_NODES; n += nw) {
        int nn = n + nw;
        int4 onext = make_int4(0, 0, 0, 0);
        u64 pnext = 0ull;
        if (nn < N_NODES) {
            onext = ((const int4*)offs)[nn];
            int nbeg = __builtin_amdgcn_readfirstlane(onext.x);
            int nend = __builtin_amdgcn_readfirstlane(onext.w);
            if (nbeg + lane < nend) pnext = pay[nbeg + lane];   // overlaps compute
        }
        int beg = __builtin_amdgcn_readfirstlane(o.x);
        int y   = __builtin_amdgcn_readfirstlane(o.y);
        int z   = __builtin_amdgcn_readfirstlane(o.z);
        int end = __builtin_amdgcn_readfirstlane(o.w);
        float2 xa = make_float2(0.f, 0.f), xb = make_float2(0.f, 0.f), xc = make_float2(0.f, 0.f);
        float ea = 0.f, eb = 0.f, ec = 0.f;

        u64 pcur = p;
        for (int base = beg; base < end; base += 64) {
            int m = end - base; if (m > 64) m = 64;
            if (base != beg) pcur = (lane < m) ? pay[base + lane] : 0ull;  // rare (deg>64)
            int plo = (int)(unsigned)pcur;            // src
            int phi = (int)(unsigned)(pcur >> 32);    // edge id
            for (int j = 0; j < m; j += 16) {
                int sgp[8], egp[8];
#pragma unroll
                for (int q = 0; q < 8; ++q) {
                    int baddr = ((j + 2 * q) << 2) + h4;   // lane idx j+2q+half, x4
                    sgp[q] = __builtin_amdgcn_ds_bpermute(baddr, plo);
                    egp[q] = __builtin_amdgcn_ds_bpermute(baddr, phi);
                }
                unsigned xv[8];
                float evv[8];
#pragma unroll
                for (int q = 0; q < 8; ++q) {
                    xv[q]  = xo32[(unsigned)sgp[q] * 32u + (unsigned)c];
                    evv[q] = ef[(unsigned)egp[q] * 32u + (unsigned)c];
                }
#pragma unroll
                for (int q = 0; q < 8; ++q) {
                    float2 x2v = make_float2(bflo(xv[q]), bfhi(xv[q]));
                    float ev = evv[q];
                    int i0 = base + j + 2 * q;     // scalar
                    if (i0 + 1 < y) {                                   // pair in seg0
                        xa.x += x2v.x; xa.y += x2v.y; ea += ev;
                    } else if (i0 >= y && i0 + 1 < z) {                 // pair in seg1
                        xb.x += x2v.x; xb.y += x2v.y; eb += ev;
                    } else if (i0 >= z && i0 + 1 < end) {               // pair in seg2
                        xc.x += x2v.x; xc.y += x2v.y; ec += ev;
                    } else {                                            // boundary / tail
                        int idx = i0 + half;
                        bool v = idx < end;
                        float fl = v ? x2v.x : 0.f, fh = v ? x2v.y : 0.f, fe = v ? ev : 0.f;
                        if (idx < y)      { xa.x += fl; xa.y += fh; ea += fe; }
                        else if (idx < z) { xb.x += fl; xb.y += fh; eb += fe; }
                        else              { xc.x += fl; xc.y += fh; ec += fe; }
                    }
                }
            }
        }
        // fold the two halves
        xa.x += __shfl_down(xa.x, 32); xa.y += __shfl_down(xa.y, 32);
        xb.x += __shfl_down(xb.x, 32); xb.y += __shfl_down(xb.y, 32);
        xc.x += __shfl_down(xc.x, 32); xc.y += __shfl_down(xc.y, 32);
        ea   += __shfl_down(ea, 32);   eb   += __shfl_down(eb, 32);   ec += __shfl_down(ec, 32);

        if (lane < 32) {
            bf16* Bn = B + (size_t)n * KCAT;
            *(unsigned*)&Bn[2 * c]       = packbf2(xa.x, xa.y);
            *(unsigned*)&Bn[64 + 2 * c]  = packbf2(xb.x, xb.y);
            *(unsigned*)&Bn[128 + 2 * c] = packbf2(xc.x, xc.y);
            Bn[192 + c] = __float2bfloat16(ea);
            Bn[224 + c] = __float2bfloat16(eb);
            Bn[256 + c] = __float2bfloat16(ec);
        }
        o = onext;
        p = pnext;
    }
}

// ---------------------------------------------------------------------------
// final_gemm_mfma: out = B(bf16) @ Wcat(bf16 in LDS, transposed+padded).
// Staging FIX vs round 18: coalesced float4 Wm reads (thread -> row ch>>4,
// col-quad (ch&15)*4), transpose via 4x ds_write_b16. MFMA core unchanged
// (HW-verified correct in round 18).
// ---------------------------------------------------------------------------
__global__ __launch_bounds__(256) void final_gemm_mfma(const bf16* __restrict__ Bb,
                                                       const float* __restrict__ Wm,
                                                       float* __restrict__ out) {
    __shared__ short WT[64][312];   // WcatT bf16, 39 KB
    int tid = threadIdx.x;
    // stage WcatT: 4608 float4 chunks, 18 per thread, coalesced global reads
#pragma unroll
    for (int i = 0; i < 18; ++i) {
        int ch = i * 256 + tid;          // chunk id 0..4607
        int r  = ch >> 4;                // Wcat row 0..287
        int j0 = (ch & 15) * 4;          // col base 0..60
        int t, kin;
        if (r < 192) { t = r >> 6; kin = r & 63; }
        else         { int s2 = r - 192; t = s2 >> 5; kin = 64 + (s2 & 31); }
        float4 v = *(const float4*)&Wm[(t * 96 + kin) * 64 + j0];
        WT[j0 + 0][r] = sbf(v.x);
        WT[j0 + 1][r] = sbf(v.y);
        WT[j0 + 2][r] = sbf(v.z);
        WT[j0 + 3][r] = sbf(v.w);
    }
    __syncthreads();

    int w = tid >> 6, l = tid & 63;
    int lrow = l & 15;
    int lk = (l >> 4) * 8;               // k sub-offset within K=32 step
    int nbase = blockIdx.x * 64 + w * 16;
    int node = nbase + lrow;
    int nodec = (node < N_NODES) ? node : (N_NODES - 1);   // clamp (padded rows unused)
    const bf16* arow = Bb + (size_t)nodec * KCAT + lk;
    f32x4v acc0 = {0.f, 0.f, 0.f, 0.f}, acc1 = acc0, acc2 = acc0, acc3 = acc0;
#pragma unroll
    for (int kk = 0; kk < 9; ++kk) {
        bf16x8v a  = *(const bf16x8v*)(arow + kk * 32);
        bf16x8v b0 = *(const bf16x8v*)&WT[ 0 + lrow][kk * 32 + lk];
        bf16x8v b1 = *(const bf16x8v*)&WT[16 + lrow][kk * 32 + lk];
        bf16x8v b2 = *(const bf16x8v*)&WT[32 + lrow][kk * 32 + lk];
        bf16x8v b3 = *(const bf16x8v*)&WT[48 + lrow][kk * 32 + lk];
        acc0 = __builtin_amdgcn_mfma_f32_16x16x32_bf16(a, b0, acc0, 0, 0, 0);
        acc1 = __builtin_amdgcn_mfma_f32_16x16x32_bf16(a, b1, acc1, 0, 0, 0);
        acc2 = __builtin_amdgcn_mfma_f32_16x16x32_bf16(a, b2, acc2, 0, 0, 0);
        acc3 = __builtin_amdgcn_mfma_f32_16x16x32_bf16(a, b3, acc3, 0, 0, 0);
    }
    int col = l & 15;
    int row0 = (l >> 4) * 4;
#pragma unroll
    for (int r = 0; r < 4; ++r) {
        int n = nbase + row0 + r;
        if (n < N_NODES) {
            float* on = out + (size_t)n * 64;
            on[ 0 + col] = acc0[r];
            on[16 + col] = acc1[r];
            on[32 + col] = acc2[r];
            on[48 + col] = acc3[r];
        }
    }
}

// ---------------------------------------------------------------------------
// Fallback (ws tiny): direct wave-per-edge, fp32.
// ---------------------------------------------------------------------------
__global__ __launch_bounds__(256) void fallback_edge(const float* __restrict__ nf,
                                                     const float* __restrict__ ef,
                                                     const float* __restrict__ Wn,
                                                     const float* __restrict__ Wm,
                                                     const int* __restrict__ ntype,
                                                     const int* __restrict__ etype,
                                                     const int* __restrict__ eidx,
                                                     float* __restrict__ out) {
    __shared__ float wn[2 * 64 * 64];
    __shared__ float wm[3 * 96 * 64];
    for (int i = threadIdx.x; i < 2 * 64 * 64; i += 256) wn[i] = Wn[i];
    for (int i = threadIdx.x; i < 3 * 96 * 64; i += 256) wm[i] = Wm[i];
    __syncthreads();
    int wid = threadIdx.x >> 6, lane = threadIdx.x & 63;
    for (int e = blockIdx.x * 4 + wid; e < N_EDGES; e += gridDim.x * 4) {
        int t = etype[e];
        int s = eidx[e];
        int d = eidx[N_EDGES + e];
        int nt = ntype[s];
        float xs = nf[(long)s * 64 + lane];
        const float* wcol = &wn[nt * 4096 + lane];
        float xo = 0.f;
#pragma unroll 16
        for (int k = 0; k < 64; ++k) xo = fmaf(__shfl(xs, k), wcol[k * 64], xo);
        float ev = ef[(long)e * 32 + (lane & 31)];
        const float* mcol = &wm[t * 96 * 64 + lane];
        float m = 0.f;
#pragma unroll 16
        for (int k = 0; k < 64; ++k) m = fmaf(__shfl(xo, k), mcol[k * 64], m);
#pragma unroll 8
        for (int k = 0; k < 32; ++k) m = fmaf(__shfl(ev, k), mcol[(64 + k) * 64], m);
        atomicAdd(&out[(long)d * 64 + lane], m);
    }
}

// ---------------------------------------------------------------------------
extern "C" void kernel_launch(void* const* d_in, const int* in_sizes, int n_in,
                              void* d_out, int out_size, void* d_ws, size_t ws_size,
                              hipStream_t stream) {
    const float* nf    = (const float*)d_in[0];
    const float* ef    = (const float*)d_in[1];
    const float* Wn    = (const float*)d_in[2];
    const float* Wm    = (const float*)d_in[3];
    const int*   ntype = (const int*)d_in[4];
    const int*   etype = (const int*)d_in[5];
    const int*   eidx  = (const int*)d_in[6];
    float* out = (float*)d_out;

    const size_t xout_bytes = (size_t)N_NODES * 64 * 2;        // 12.8 MB bf16
    const size_t b_bytes    = (size_t)N_NODES * KCAT * 2;      // 57.6 MB bf16

    if (ws_size >= xout_bytes + b_bytes) {
        bf16* xout = (bf16*)d_ws;
        bf16* B    = (bf16*)((char*)d_ws + xout_bytes);
        // scratch in d_out (22.4 MB < 25.6 MB); final_gemm fully overwrites
        // d_out at the end of every call.
        u64* pay      = (u64*)d_out;            // 12.8 MB
        int* cnt      = (int*)(pay + N_EDGES);  // 1.6 MB
        int* offs     = cnt + NK;               // 1.6 MB
        int* partials = offs + NK;              // 2 KB (pad 512)
        int* krank    = partials + 512;         // 6.4 MB

        node_xform_g<<<(N_NODES + 63) / 64, 256, 0, stream>>>(nf, Wn, ntype, xout, cnt);
        count_rank<<<(N_EDGES + 255) / 256, 256, 0, stream>>>(eidx, etype, cnt, krank);
        scan_a<<<NBCHUNK, 256, 0, stream>>>(cnt, partials);
        scan_c<<<NBCHUNK, 256, 0, stream>>>(cnt, partials, offs);
        place_pay<<<(N_EDGES + 255) / 256, 256, 0, stream>>>(eidx, krank, offs, pay);
        aggregate_g<<<4096, 256, 0, stream>>>(pay, offs, xout, ef, B);
        final_gemm_mfma<<<(N_NODES + 63) / 64, 256, 0, stream>>>(B, Wm, out);
    } else {
        zero_buf<<<2048, 256, 0, stream>>>((float4*)d_out, (long)((size_t)out_size * 4 / 16));
        fallback_edge<<<4096, 256, 0, stream>>>(nf, ef, Wn, Wm, ntype, etype, eidx, out);
    }
}